// Round 2
// baseline (247.787 us; speedup 1.0000x reference)
//
#include <hip/hip_runtime.h>

// out[b,s,d] = alpha*sum_{j=1..P} beta^{j-1} x[b,s-j,d] + pf[d] + pb[((s>>5)-d)&31]
//
// PIPELINED READ-ONCE version. R1 (read-once, shfl-lag) hit ~80 us/dispatch but only
// 3.35 TB/s: load->barrier->scan->barrier->store with __syncthreads() fully drains
// vmcnt at every phase edge (compiler emits s_waitcnt vmcnt(0) before s_barrier), so
// the memory pipe idles during scans and store-drain never overlaps successor loads.
// Here each block owns ROWS=4 consecutive batch rows and software-pipelines them:
//   row r body: [issue row r+1 loads into other reg buffer] -> A(r) -> lgkmcnt(0) ->
//               raw s_barrier -> serial scan -> lgkmcnt(0) -> raw s_barrier ->
//               pass B stores(r) (+ shfl-lag recurrence)
// Raw __builtin_amdgcn_s_barrier + LDS-only waitcnt keeps the 16 prefetch loads in
// flight across both barriers (they protect only sA/sC). Stores of row r drain under
// loads of row r+1. Grid = B/4 = 256 = one block per CU; __launch_bounds__(512,2)
// allows the 128-VGPR double buffer (xra/xrb). Numerics bit-identical to R1.

typedef float f32x4 __attribute__((ext_vector_type(4)));

constexpr int S    = 1024;
constexpr int D    = 32;
constexpr int CL   = 16;              // 16-runs stay inside one 32-block => s>>5 const
constexpr int NCH  = S / CL;          // 64 chunks
constexpr int LAG  = 8;               // P / CL
constexpr int NTHR = NCH * (D / 4);   // 512
constexpr int ROWS = 4;               // batch rows per block (pipeline depth)

__global__ __launch_bounds__(NTHR, 2)
void attn_pred_kernel(const float* __restrict__ x,
                      const float* __restrict__ alpha_p,
                      const float* __restrict__ beta_p,
                      const float* __restrict__ pos_fwd,
                      const float* __restrict__ pos_bwd,
                      const int*   __restrict__ past_p,
                      float* __restrict__ out, int B)
{
    __shared__ f32x4 sA[NCH][D / 4];  // 4 KiB: pure chunk sums
    __shared__ f32x4 sC[NCH][D / 4];  // 4 KiB: exclusive carries

    const int tid  = threadIdx.x;
    const int lane = tid & 63;
    const int wv   = tid >> 6;        // wave 0..7
    const int g    = lane >> 3;       // lag-group 0..7 within wave
    const int dg   = lane & 7;        // float4 group over d
    const int c    = g * 8 + wv;      // chunk 0..63; chunk c-LAG == lane-8, same wave
    const int s0   = c * CL;

    const float alpha = alpha_p[0];
    const float beta  = beta_p[0];
    const int   P     = past_p[0];    // 128

    // beta^P by squaring (double), beta^CL by 4 squarings
    double bb = (double)beta, bpd = 1.0;
    for (int e = P; e; e >>= 1) { if (e & 1) bpd *= bb; bb *= bb; }
    const float bP = (float)bpd;
    double b16 = (double)beta;
    for (int i = 0; i < 4; ++i) b16 *= b16;
    const float bCL = (float)b16;     // beta^16
    const float aP  = alpha * bP;     // alpha*beta^P
    const float m   = (g > 0) ? -aP : 0.f;  // lanes 0..7: shfl_up returns own value, killed

    // positional bias (s>>5 == c>>1, constant over the chunk) — row-independent
    const int d0 = dg * 4;
    const int q  = c >> 1;
    const f32x4 pf = reinterpret_cast<const f32x4*>(pos_fwd)[dg];
    f32x4 add;
    add.x = pf.x + pos_bwd[(q - (d0 + 0)) & (D - 1)];
    add.y = pf.y + pos_bwd[(q - (d0 + 1)) & (D - 1)];
    add.z = pf.z + pos_bwd[(q - (d0 + 2)) & (D - 1)];
    add.w = pf.w + pos_bwd[(q - (d0 + 3)) & (D - 1)];

    const size_t rowStride = (size_t)S * (D / 4);
    const int    b0        = blockIdx.x * ROWS;
    const f32x4* xg0 = reinterpret_cast<const f32x4*>(x)
                       + (size_t)b0 * rowStride + dg;
    f32x4*       og0 = reinterpret_cast<f32x4*>(out)
                       + (size_t)b0 * rowStride + (size_t)s0 * (D / 4) + dg;

    f32x4 xra[CL], xrb[CL];           // ping-pong row buffers (64+64 VGPR)

    // prologue: load row 0 (b0 < B guaranteed by grid sizing)
    #pragma unroll
    for (int i = 0; i < CL; ++i)
        xra[i] = xg0[(s0 + i) * (D / 4)];

// Row body. XR = current row's regs, XN = next row's regs, R = compile-time row idx.
// Macro (not pointer swap) so every register-array index is compile-time constant.
#define ROW_BODY(XR, XN, R)                                                      \
  if (b0 + (R) < B) {                                                            \
    /* issue next row's loads FIRST: they stream under everything below */       \
    if (((R) + 1 < ROWS) && (b0 + (R) + 1 < B)) {                                \
      const f32x4* xgn = xg0 + ((R) + 1) * rowStride;                            \
      _Pragma("unroll")                                                          \
      for (int i = 0; i < CL; ++i) XN[i] = xgn[(s0 + i) * (D / 4)];              \
    }                                                                            \
    /* pass A: decayed chunk sum from registers (waits only XR's vmcnt) */       \
    f32x4 A = {0.f, 0.f, 0.f, 0.f};                                              \
    _Pragma("unroll")                                                            \
    for (int i = 0; i < CL; ++i) {                                               \
      A.x = fmaf(beta, A.x, XR[i].x);                                            \
      A.y = fmaf(beta, A.y, XR[i].y);                                            \
      A.z = fmaf(beta, A.z, XR[i].z);                                            \
      A.w = fmaf(beta, A.w, XR[i].w);                                            \
    }                                                                            \
    sA[c][dg] = A;                                                               \
    asm volatile("s_waitcnt lgkmcnt(0)" ::: "memory"); /* LDS only — loads fly */\
    __builtin_amdgcn_s_barrier();                                                \
    __builtin_amdgcn_sched_barrier(0);                                           \
    /* scan (8 threads): exclusive carries over 64 chunks */                     \
    if (tid < D / 4) {                                                           \
      f32x4 run = {0.f, 0.f, 0.f, 0.f};                                          \
      for (int cc = 0; cc < NCH; ++cc) {                                         \
        sC[cc][tid] = run;                                                       \
        const f32x4 Ac = sA[cc][tid];                                            \
        f32x4 z;                                                                 \
        if (cc >= LAG) {                                                         \
          const f32x4 Al = sA[cc - LAG][tid];                                    \
          z.x = alpha * fmaf(-bP, Al.x, Ac.x);                                   \
          z.y = alpha * fmaf(-bP, Al.y, Ac.y);                                   \
          z.z = alpha * fmaf(-bP, Al.z, Ac.z);                                   \
          z.w = alpha * fmaf(-bP, Al.w, Ac.w);                                   \
        } else {                                                                 \
          z.x = alpha * Ac.x; z.y = alpha * Ac.y;                                \
          z.z = alpha * Ac.z; z.w = alpha * Ac.w;                                \
        }                                                                        \
        run.x = fmaf(bCL, run.x, z.x);                                           \
        run.y = fmaf(bCL, run.y, z.y);                                           \
        run.z = fmaf(bCL, run.z, z.z);                                           \
        run.w = fmaf(bCL, run.w, z.w);                                           \
      }                                                                          \
    }                                                                            \
    asm volatile("s_waitcnt lgkmcnt(0)" ::: "memory");                           \
    __builtin_amdgcn_s_barrier();                                                \
    __builtin_amdgcn_sched_barrier(0);                                           \
    f32x4 y = sC[c][dg];                                                         \
    /* pass B: emit 16 outputs; lagged x via intra-wave shuffle (read-once) */   \
    f32x4* og = og0 + (R) * rowStride;                                           \
    _Pragma("unroll")                                                            \
    for (int i = 0; i < CL; ++i) {                                               \
      f32x4 o;                                                                   \
      o.x = y.x + add.x; o.y = y.y + add.y;                                      \
      o.z = y.z + add.z; o.w = y.w + add.w;                                      \
      __builtin_nontemporal_store(o, &og[i * (D / 4)]);                          \
      f32x4 xl;                                                                  \
      xl.x = __shfl_up(XR[i].x, 8);                                              \
      xl.y = __shfl_up(XR[i].y, 8);                                              \
      xl.z = __shfl_up(XR[i].z, 8);                                              \
      xl.w = __shfl_up(XR[i].w, 8);                                              \
      y.x = fmaf(beta, y.x, fmaf(alpha, XR[i].x, m * xl.x));                     \
      y.y = fmaf(beta, y.y, fmaf(alpha, XR[i].y, m * xl.y));                     \
      y.z = fmaf(beta, y.z, fmaf(alpha, XR[i].z, m * xl.z));                     \
      y.w = fmaf(beta, y.w, fmaf(alpha, XR[i].w, m * xl.w));                     \
    }                                                                            \
  }

    ROW_BODY(xra, xrb, 0)
    ROW_BODY(xrb, xra, 1)
    ROW_BODY(xra, xrb, 2)
    ROW_BODY(xrb, xra, 3)
#undef ROW_BODY
}

extern "C" void kernel_launch(void* const* d_in, const int* in_sizes, int n_in,
                              void* d_out, int out_size, void* d_ws, size_t ws_size,
                              hipStream_t stream) {
    const float* x  = (const float*)d_in[0];
    const float* al = (const float*)d_in[1];
    const float* be = (const float*)d_in[2];
    const float* pf = (const float*)d_in[3];
    const float* pb = (const float*)d_in[4];
    const int*   ps = (const int*)d_in[5];
    float* out = (float*)d_out;

    const int B = in_sizes[0] / (S * D);   // 1024
    const int grid = (B + ROWS - 1) / ROWS; // 256 -> one block per CU
    attn_pred_kernel<<<dim3(grid), NTHR, 0, stream>>>(x, al, be, pf, pb, ps, out, B);
}